// Round 7
// baseline (851.665 us; speedup 1.0000x reference)
//
#include <hip/hip_runtime.h>

typedef unsigned short u16;
typedef __attribute__((ext_vector_type(8))) short short8;
typedef __attribute__((ext_vector_type(4))) float f32x4;

#define NROW 8192

__device__ __forceinline__ float bf2f(u16 h) {
  unsigned u = ((unsigned)h) << 16;
  return __builtin_bit_cast(float, u);
}
// mode-aware load: f32 ? fp32 storage : bf16 storage (upcast)
__device__ __forceinline__ float ldf(const void* p, size_t i, int f32) {
  return f32 ? ((const float*)p)[i] : bf2f(((const u16*)p)[i]);
}
// fp32 -> bf16 round-to-nearest-even
__device__ __forceinline__ u16 f2bf(float f) {
  unsigned b = __builtin_bit_cast(unsigned, f);
  b += 0x7FFFu + ((b >> 16) & 1u);
  return (u16)(b >> 16);
}

// ---- storage-dtype detection on x (N(0,1)).
__global__ void detect3(const u16* __restrict__ xr, unsigned* __restrict__ mode) {
  __shared__ int zc, bg;
  int t = threadIdx.x;   // 256
  if (t == 0) { zc = 0; bg = 0; }
  __syncthreads();
  int zeros_even = 0; int big = 0;
  for (int i = t; i < 4096; i += 256) {
    u16 v = xr[i];
    if (!(i & 1) && v == 0) zeros_even++;
    if (fabsf(bf2f(v)) > 1e6f) big = 1;
  }
  atomicAdd(&zc, zeros_even);
  if (big) atomicOr(&bg, 1);
  __syncthreads();
  if (t == 0) *mode = (zc > 512 || bg) ? 1u : 0u;   // 1 = fp32 storage
}

// ---- adj storage detection (u32 pair pattern 0x00003F80 unique to bf16).
__global__ void detect_adj(const unsigned* __restrict__ a, unsigned* __restrict__ amode) {
  __shared__ int clo;
  int t = threadIdx.x;   // 256
  if (t == 0) clo = 0;
  __syncthreads();
  int c = 0;
  for (int i = t; i < 4096; i += 256)
    if (a[i] == 0x00003F80u) c++;
  atomicAdd(&clo, c);
  __syncthreads();
  if (t == 0) *amode = (clo > 32) ? 1u : 0u;   // 1 = bf16 storage
}

// ---- adjacency -> bitmask (8 MB). byte b covers elements [b*8, b*8+8),
// bit q = (elem b*8+q != 0). Fully coalesced read/write; one streaming pass.
__global__ __launch_bounds__(256) void adj_bits(const void* __restrict__ adj,
    unsigned char* __restrict__ bits, const unsigned* __restrict__ amodep) {
  int amode = (int)*amodep;
  for (size_t b = (size_t)blockIdx.x * 256 + threadIdx.x; b < 8388608; b += 524288) {
    size_t e0 = b * 8;
    unsigned byte = 0;
    if (amode == 0) {          // u32/f32 storage
      int4 a0 = *(const int4*)((const int*)adj + e0);
      int4 a1 = *(const int4*)((const int*)adj + e0 + 4);
      byte = (a0.x != 0) | ((a0.y != 0) << 1) | ((a0.z != 0) << 2) | ((a0.w != 0) << 3) |
             ((a1.x != 0) << 4) | ((a1.y != 0) << 5) | ((a1.z != 0) << 6) | ((a1.w != 0) << 7);
    } else {                   // bf16 storage
      ushort4 a0 = *(const ushort4*)((const u16*)adj + e0);
      ushort4 a1 = *(const ushort4*)((const u16*)adj + e0 + 4);
      byte = (a0.x != 0) | ((a0.y != 0) << 1) | ((a0.z != 0) << 2) | ((a0.w != 0) << 3) |
             ((a1.x != 0) << 4) | ((a1.y != 0) << 5) | ((a1.z != 0) << 6) | ((a1.w != 0) << 7);
    }
    bits[b] = (unsigned char)byte;
  }
}

// C[M x N] fp32 = Abf[M x K] @ BT[N x K]^T, all bf16 operands, MFMA, no LDS.
// grid (N/64, M/64), 256 threads; wave w owns rows w*16..+15, 4 n-tiles.
__global__ __launch_bounds__(256) void gemm_mfma(const u16* __restrict__ Abf,
    const u16* __restrict__ BT, float* __restrict__ C, int K, int N) {
  int tid = threadIdx.x;
  int l = tid & 63, w = tid >> 6;
  int m0 = blockIdx.y * 64, n0 = blockIdx.x * 64;
  const u16* arow = Abf + (size_t)(m0 + w * 16 + (l & 15)) * K + (l >> 4) * 8;
  const u16* brow = BT + (size_t)(n0 + (l & 15)) * K + (l >> 4) * 8;
  f32x4 acc[4];
#pragma unroll
  for (int nt = 0; nt < 4; ++nt) acc[nt] = (f32x4){0.f, 0.f, 0.f, 0.f};
  for (int k0 = 0; k0 < K; k0 += 32) {
    short8 a = *(const short8*)(arow + k0);
#pragma unroll
    for (int nt = 0; nt < 4; ++nt) {
      short8 b = *(const short8*)(brow + (size_t)nt * 16 * K + k0);
      acc[nt] = __builtin_amdgcn_mfma_f32_16x16x32_bf16(a, b, acc[nt], 0, 0, 0);
    }
  }
  // C/D layout: col = lane&15, row = (lane>>4)*4 + q
#pragma unroll
  for (int nt = 0; nt < 4; ++nt)
#pragma unroll
    for (int q = 0; q < 4; ++q)
      C[(size_t)(m0 + w * 16 + (l >> 4) * 4 + q) * N + n0 + nt * 16 + (l & 15)] =
          acc[nt][q];
}

// Layer-2/3 dual GEMM: C{0,1}[8192 x 64] fp32 = hbf[8192 x 256] @ BT{0,1}[64 x 256]^T.
__global__ __launch_bounds__(256) void gemm2_dual(const u16* __restrict__ Abf,
    const u16* __restrict__ BT0, const u16* __restrict__ BT1,
    float* __restrict__ C0, float* __restrict__ C1) {
  const int K = 256, N = 64;
  const u16* BT = blockIdx.x ? BT1 : BT0;
  float* C = blockIdx.x ? C1 : C0;
  int tid = threadIdx.x, l = tid & 63, w = tid >> 6;
  int m0 = blockIdx.y * 64;
  const u16* arow = Abf + (size_t)(m0 + w * 16 + (l & 15)) * K + (l >> 4) * 8;
  const u16* brow = BT + (size_t)(l & 15) * K + (l >> 4) * 8;
  f32x4 acc[4];
#pragma unroll
  for (int nt = 0; nt < 4; ++nt) acc[nt] = (f32x4){0.f, 0.f, 0.f, 0.f};
  for (int k0 = 0; k0 < K; k0 += 32) {
    short8 a = *(const short8*)(arow + k0);
#pragma unroll
    for (int nt = 0; nt < 4; ++nt) {
      short8 b = *(const short8*)(brow + (size_t)nt * 16 * K + k0);
      acc[nt] = __builtin_amdgcn_mfma_f32_16x16x32_bf16(a, b, acc[nt], 0, 0, 0);
    }
  }
#pragma unroll
  for (int nt = 0; nt < 4; ++nt)
#pragma unroll
    for (int q = 0; q < 4; ++q)
      C[(size_t)(m0 + w * 16 + (l >> 4) * 4 + q) * N + nt * 16 + (l & 15)] = acc[nt][q];
}

// bf16 copy of a mode-aware buffer (8 elems/thread). n8 = elems/8.
__global__ __launch_bounds__(256) void convert_bf16(const void* __restrict__ in,
    u16* __restrict__ out, int n8, const unsigned* __restrict__ modep) {
  int f32 = (int)*modep;
  int i = blockIdx.x * 256 + threadIdx.x;
  if (i >= n8) return;
  if (f32) {
    float4 v0 = ((const float4*)in)[(size_t)i * 2];
    float4 v1 = ((const float4*)in)[(size_t)i * 2 + 1];
    ushort4 o0 = {f2bf(v0.x), f2bf(v0.y), f2bf(v0.z), f2bf(v0.w)};
    ushort4 o1 = {f2bf(v1.x), f2bf(v1.y), f2bf(v1.z), f2bf(v1.w)};
    ((ushort4*)out)[(size_t)i * 2] = o0;
    ((ushort4*)out)[(size_t)i * 2 + 1] = o1;
  } else {
    ((int4*)out)[i] = ((const int4*)in)[i];   // already bf16: raw copy
  }
}

// transpose + bf16 convert: in fp32 [M][F] -> out bf16 [F][M]. grid (M/32, F/32).
__global__ __launch_bounds__(256) void transpose_bf16(const float* __restrict__ in,
    u16* __restrict__ out, int M, int F) {
  __shared__ float t[32][33];
  int m0 = blockIdx.x * 32, f0 = blockIdx.y * 32;
  int c = threadIdx.x & 31, r = threadIdx.x >> 5;   // r = 0..7
  for (int rr = r; rr < 32; rr += 8)
    t[rr][c] = in[(size_t)(m0 + rr) * F + f0 + c];
  __syncthreads();
  for (int rr = r; rr < 32; rr += 8)
    out[(size_t)(f0 + rr) * M + m0 + c] = f2bf(t[c][rr]);
}

// dual fp32->bf16 transpose (whmu/whlv -> whmuT/whlvT). grid (M/32, F/32, 2).
__global__ __launch_bounds__(256) void transpose_pair(const float* __restrict__ in0,
    const float* __restrict__ in1, u16* __restrict__ out0, u16* __restrict__ out1,
    int M, int F) {
  const float* in = blockIdx.z ? in1 : in0;
  u16* out = blockIdx.z ? out1 : out0;
  __shared__ float t[32][33];
  int m0 = blockIdx.x * 32, f0 = blockIdx.y * 32;
  int c = threadIdx.x & 31, r = threadIdx.x >> 5;
  for (int rr = r; rr < 32; rr += 8)
    t[rr][c] = in[(size_t)(m0 + rr) * F + f0 + c];
  __syncthreads();
  for (int rr = r; rr < 32; rr += 8)
    out[(size_t)(f0 + rr) * M + m0 + c] = f2bf(t[c][rr]);
}

// transpose + bf16 convert from a RAW (mode-aware) buffer. grid (M/32, F/32).
__global__ __launch_bounds__(256) void transpose_any(const void* __restrict__ in,
    u16* __restrict__ out, int M, int F, const unsigned* __restrict__ modep) {
  int f32 = (int)*modep;
  __shared__ u16 t[32][33];
  int m0 = blockIdx.x * 32, f0 = blockIdx.y * 32;
  int c = threadIdx.x & 31, r = threadIdx.x >> 5;
  for (int rr = r; rr < 32; rr += 8)
    t[rr][c] = f2bf(ldf(in, (size_t)(m0 + rr) * F + f0 + c, f32));
  __syncthreads();
  for (int rr = r; rr < 32; rr += 8)
    out[(size_t)(f0 + rr) * M + m0 + c] = t[c][rr];
}

// dual raw transpose (Wmu/Wlv -> WmuT/WlvT). grid (M/32, F/32, 2).
__global__ __launch_bounds__(256) void transpose_w2(const void* __restrict__ in0,
    const void* __restrict__ in1, u16* __restrict__ out0, u16* __restrict__ out1,
    int M, int F, const unsigned* __restrict__ modep) {
  int f32 = (int)*modep;
  const void* in = blockIdx.z ? in1 : in0;
  u16* out = blockIdx.z ? out1 : out0;
  __shared__ u16 t[32][33];
  int m0 = blockIdx.x * 32, f0 = blockIdx.y * 32;
  int c = threadIdx.x & 31, r = threadIdx.x >> 5;
  for (int rr = r; rr < 32; rr += 8)
    t[rr][c] = f2bf(ldf(in, (size_t)(m0 + rr) * F + f0 + c, f32));
  __syncthreads();
  for (int rr = r; rr < 32; rr += 8)
    out[(size_t)(f0 + rr) * M + m0 + c] = t[c][rr];
}

// s_i = Wh_i . a[:F], d_i = Wh_i . a[F:] (Wh fp32, a raw). NO atomics.
__global__ __launch_bounds__(256) void sd_f32(const float* __restrict__ Wh,
    const void* __restrict__ a2, float* __restrict__ s, float* __restrict__ d,
    int F, const unsigned* __restrict__ modep) {
  int f32 = (int)*modep;
  int row = blockIdx.x * 4 + (threadIdx.x >> 6);
  int l = threadIdx.x & 63;
  float ss = 0.f, dd = 0.f;
  for (int k = l; k < F; k += 64) {
    float wv = Wh[(size_t)row * F + k];
    ss += wv * ldf(a2, k, f32);
    dd += wv * ldf(a2, F + k, f32);
  }
#pragma unroll
  for (int off = 32; off > 0; off >>= 1) {
    ss += __shfl_down(ss, off, 64);
    dd += __shfl_down(dd, off, 64);
  }
  if (l == 0) { s[row] = ss; d[row] = dd; }
}

// dual s/d for layers 2/3 (F = 64). grid (2048, 2). NO atomics.
__global__ __launch_bounds__(256) void sd_dual(const float* __restrict__ Wh0,
    const float* __restrict__ Wh1, const void* __restrict__ a0,
    const void* __restrict__ a1, float* __restrict__ s0, float* __restrict__ s1,
    float* __restrict__ d0, float* __restrict__ d1,
    const unsigned* __restrict__ modep) {
  int f32 = (int)*modep;
  int L = blockIdx.y;
  const float* Wh = L ? Wh1 : Wh0;
  const void* a2 = L ? a1 : a0;
  int row = blockIdx.x * 4 + (threadIdx.x >> 6);
  int l = threadIdx.x & 63;
  float wv = Wh[(size_t)row * 64 + l];
  float ss = wv * ldf(a2, l, f32);
  float dd = wv * ldf(a2, 64 + l, f32);
#pragma unroll
  for (int off = 32; off > 0; off >>= 1) {
    ss += __shfl_down(ss, off, 64);
    dd += __shfl_down(dd, off, 64);
  }
  if (l == 0) { (L ? s1 : s0)[row] = ss; (L ? d1 : d0)[row] = dd; }
}

// Dmax: single block per array, LDS tree, plain store. grid = #arrays.
__global__ __launch_bounds__(256) void dmax_reduce(const float* __restrict__ da,
    const float* __restrict__ db, float* __restrict__ cells) {
  const float* d = blockIdx.x ? db : da;
  __shared__ float red[256];
  float m = -3.4e38f;
  for (int i = threadIdx.x; i < NROW; i += 256) m = fmaxf(m, d[i]);
  red[threadIdx.x] = m;
  __syncthreads();
#pragma unroll
  for (int sft = 128; sft > 0; sft >>= 1) {
    if (threadIdx.x < sft) red[threadIdx.x] = fmaxf(red[threadIdx.x], red[threadIdx.x + sft]);
    __syncthreads();
  }
  if (threadIdx.x == 0) cells[blockIdx.x * 16] = red[0];
}

// swizzled P-fragment LDS byte offset:
// slot = L*16 + ks*2 + mh (1KB each, ks 0..7); within: [row 0..15][kg 0..3] x
// 8 bf16, kg XOR'd with (row>>1)&3 to spread banks on b128 write/read.
__device__ __forceinline__ int pa_off(int L, int ks, int mh, int row, int kg) {
  return ((L * 16 + ks * 2 + mh) << 10) + (row << 6) + ((kg ^ ((row >> 1) & 3)) << 4);
}

// Flash GAT layer(s) on MFMA — JS=1: each block owns 32 output rows COMPLETELY.
// grid = 256 blocks x 1024 threads (16 waves, 4/SIMD). ZERO global atomics.
// j-tile = 256 per iteration (NIT=32). Adjacency from the 8 MB BITMASK
// (1 byte/thread/iter, depth-2 reg prefetch) -> whT stays L2-resident.
// Pipeline: raw s_barrier + lgkmcnt-only fence, PA double-buffered, setprio.
// NL=1 (FDIM=256): wave w: mh = w>>3, n-tiles (w&7)*2..+1 (2 MFMA per ds_read).
// NL=2 (FDIM=64): layer = w>>3; within: nt = w&3, mh = (w>>2)&1.
template <int NL>
__global__ __launch_bounds__(1024) void flash_mfma(
    const u16* __restrict__ whTa, const u16* __restrict__ whTb,   // bf16 [FDIM][NROW]
    const float* __restrict__ sa, const float* __restrict__ da,
    const float* __restrict__ sb, const float* __restrict__ db,
    const float* __restrict__ cella, const float* __restrict__ cellb,
    const unsigned char* __restrict__ abits,
    void* __restrict__ o0, void* __restrict__ o1,
    void* __restrict__ o2, void* __restrict__ o3) {
  constexpr int NIT = NROW / 256;            // 32 iterations
  constexpr int NTW = (NL == 1) ? 2 : 1;     // n-tiles per wave
  constexpr int FDIM = (NL == 1) ? 256 : 64;
  __shared__ __align__(16) char PA[2][NL * 16384];  // double-buffered P frags
  __shared__ __align__(16) float dd_[NL][NROW];     // full d_j (prologue stage)
  __shared__ float sv_[NL][32], Ms_[NL][32], ls_[NL][32];
  int tid = threadIdx.x;
  int r0 = blockIdx.x * 32;
  if (tid < 32 * NL) {
    int L = tid >> 5, i = tid & 31;
    float Dm = L ? *cellb : *cella;
    float t0 = (L ? sb : sa)[r0 + i];
    sv_[L][i] = t0;
    float m = t0 + Dm;
    Ms_[L][i] = fmaxf(m, 0.2f * m);   // lrelu(s_i + Dmax) >= all e[i,:]
  }
  // stage the full d_j array (float4 coalesced)
  for (int u = tid; u < NL * (NROW / 4); u += 1024) {
    int L = u / (NROW / 4), uu = u - L * (NROW / 4);
    ((float4*)dd_[L])[uu] = ((const float4*)(L ? db : da))[uu];
  }
  __syncthreads();
  // score-phase mapping: 32 rows x 32 j-octets (8 j each)
  int sr = tid >> 5, sjo = tid & 31;
  int ks_w = sjo >> 2, kg_w = sjo & 3, mh_w = sr >> 4, row_w = sr & 15;
  // PV-phase mapping
  int l = tid & 63, w = tid >> 6;            // w = 0..15
  int layer = (NL == 1) ? 0 : (w >> 3);
  int mh_p  = (NL == 1) ? (w >> 3) : ((w >> 2) & 1);
  int ntb   = (NL == 1) ? ((w & 7) * 2) : (w & 3);
  const u16* whT = layer ? whTb : whTa;
  f32x4 acc[NTW];
#pragma unroll
  for (int n = 0; n < NTW; ++n) acc[n] = (f32x4){0.f, 0.f, 0.f, 0.f};
  float psum[NL];
#pragma unroll
  for (int L = 0; L < NL; ++L) psum[L] = 0.f;
  int bofs = (r0 + sr) * 1024 + sjo;         // bitmask byte index (32 B/iter)

  // adjacency-bit prefetch: depth 2 (static rotation)
  unsigned char abA = abits[bofs];
  unsigned char abB = abits[bofs + 32];
  for (int it = 0; it < NIT; ++it) {
    int j0 = it * 256;
    int cur = it & 1;
    // B fragments for this tile (issued first; L2-hit latency hidden by score)
    short8 bfr[8][NTW];
#pragma unroll
    for (int ks = 0; ks < 8; ++ks) {
      size_t jcol = (size_t)(j0 + ks * 32 + (l >> 4) * 8);
#pragma unroll
      for (int nt = 0; nt < NTW; ++nt)
        bfr[ks][nt] =
            *(const short8*)&whT[(size_t)((ntb + nt) * 16 + (l & 15)) * NROW + jcol];
    }
    // prefetch adjacency bits two iterations ahead
    unsigned char abN = abB;
    if (it + 2 < NIT) abN = abits[bofs + (it + 2) * 32];
    // ---- score phase: P[sr, j0+sjo*8 .. +7] in bf16 into PA[cur]
    char* pab = PA[cur];
#pragma unroll
    for (int L = 0; L < NL; ++L) {
      float sv = sv_[L][sr], Mr = Ms_[L][sr];
      float4 dv0 = *(const float4*)&dd_[L][j0 + sjo * 8];
      float4 dv1 = *(const float4*)&dd_[L][j0 + sjo * 8 + 4];
      float dvv[8] = {dv0.x, dv0.y, dv0.z, dv0.w, dv1.x, dv1.y, dv1.z, dv1.w};
      short8 pk;
      float ps = 0.f;
#pragma unroll
      for (int q = 0; q < 8; ++q) {
        float t = sv + dvv[q];
        float e = fmaxf(t, 0.2f * t) - Mr;           // <= 0
        float p = ((abA >> q) & 1) ? __expf(e) : 0.f;
        ps += p;
        pk[q] = (short)f2bf(p);
      }
      psum[L] += ps;
      *(short8*)(pab + pa_off(L, ks_w, mh_w, row_w, kg_w)) = pk;
    }
    // LDS-only fence + raw barrier: global loads stay outstanding
    asm volatile("s_waitcnt lgkmcnt(0)" ::: "memory");
    __builtin_amdgcn_s_barrier();
    __builtin_amdgcn_sched_barrier(0);
    // ---- PV phase: acc += P * WhT^T (MFMA)
    __builtin_amdgcn_s_setprio(1);
#pragma unroll
    for (int ks = 0; ks < 8; ++ks) {
      short8 a = *(const short8*)(pab + pa_off(layer, ks, mh_p, l & 15, l >> 4));
#pragma unroll
      for (int nt = 0; nt < NTW; ++nt)
        acc[nt] = __builtin_amdgcn_mfma_f32_16x16x32_bf16(a, bfr[ks][nt],
                                                          acc[nt], 0, 0, 0);
    }
    __builtin_amdgcn_s_setprio(0);
    // no second barrier: next score writes PA[cur^1]; its previous readers
    // (PV at it-1) completed before this iteration's barrier.
    abA = abB; abB = abN;
  }
  // ---- lsum: per-thread psum -> LDS (reuse PA) -> per-row sum (no atomics)
  __syncthreads();                    // last PV reads of PA done
  float* red = (float*)PA;
#pragma unroll
  for (int L = 0; L < NL; ++L) red[L * 1024 + tid] = psum[L];
  __syncthreads();
  if (tid < 32 * NL) {
    int L = tid >> 5, r = tid & 31;
    float t = 0.f;
#pragma unroll
    for (int q = 0; q < 32; ++q) t += red[L * 1024 + r * 32 + q];
    ls_[L][r] = t;
  }
  __syncthreads();
  // ---- fused epilogue (C/D layout: col=lane&15, row=(lane>>4)*4+q)
  if constexpr (NL == 1) {
    u16* hb = (u16*)o0;               // bf16 h = elu(acc/lsum)
#pragma unroll
    for (int nt = 0; nt < NTW; ++nt)
#pragma unroll
      for (int q = 0; q < 4; ++q) {
        int r = mh_p * 16 + (l >> 4) * 4 + q;
        int c = (ntb + nt) * 16 + (l & 15);
        float x = acc[nt][q] / ls_[0][r];
        x = (x > 0.f) ? x : (__expf(x) - 1.f);
        hb[(size_t)(r0 + r) * FDIM + c] = f2bf(x);
      }
  } else {
    float* of = (float*)(layer ? o2 : o0);   // ws copy
    float* od = (float*)(layer ? o3 : o1);   // d_out region
#pragma unroll
    for (int q = 0; q < 4; ++q) {
      int r = mh_p * 16 + (l >> 4) * 4 + q;
      int c = ntb * 16 + (l & 15);
      float x = acc[0][q] / ls_[layer][r];
      size_t idx = (size_t)(r0 + r) * FDIM + c;
      of[idx] = x;
      od[idx] = x;
    }
  }
}

// logits = (mu + eps*exp(0.5*logvar)) @ Wc + bc. 256 blocks x 32 rows.
__global__ __launch_bounds__(256) void logits_f32(const float* __restrict__ mu,
    const float* __restrict__ lv, const void* __restrict__ eps,
    const void* __restrict__ Wc, const void* __restrict__ bcv,
    float* __restrict__ outL, const unsigned* __restrict__ modep) {
  int f32 = (int)*modep;
  __shared__ float zs[32 * 64];
  __shared__ float wcs[64 * 16];
  int tid = threadIdx.x;
  for (int i = tid; i < 1024; i += 256) wcs[i] = ldf(Wc, i, f32);
  int row0 = blockIdx.x * 32;
  for (int i = tid; i < 2048; i += 256) {
    int r = i >> 6, c = i & 63;
    size_t g = (size_t)(row0 + r) * 64 + c;
    zs[i] = mu[g] + ldf(eps, g, f32) * __expf(0.5f * lv[g]);
  }
  __syncthreads();
  for (int it = tid; it < 512; it += 256) {
    int r = it >> 4, oc = it & 15;
    float a = ldf(bcv, oc, f32);
    for (int c = 0; c < 64; ++c) a += zs[r * 64 + c] * wcs[c * 16 + oc];
    outL[(size_t)(row0 + r) * 16 + oc] = a;
  }
}

extern "C" void kernel_launch(void* const* d_in, const int* in_sizes, int n_in,
                              void* d_out, int out_size, void* d_ws, size_t ws_size,
                              hipStream_t stream) {
  (void)out_size; (void)ws_size;
  // ---- size-based input resolution (robust to permutation; ties in dict order)
  int ix = 0, iadj = 1, ieps = 2, iW1 = 3, ia1 = 4, iWmu = 5, iamu = 6,
      iWlv = 7, ialv = 8, iWc = 9, ibc = 10;
  {
    int fmu = -1, flv = -1, fam = -1, fal = -1;
    for (int i = 0; i < n_in; ++i) {
      switch (in_sizes[i]) {
        case 67108864: iadj = i; break;
        case 4194304:  ix   = i; break;
        case 524288:   ieps = i; break;
        case 131072:   iW1  = i; break;
        case 512:      ia1  = i; break;
        case 1024:     iWc  = i; break;
        case 16:       ibc  = i; break;
        case 16384:    if (fmu < 0) fmu = i; else flv = i; break;
        case 128:      if (fam < 0) fam = i; else fal = i; break;
        default: break;
      }
    }
    if (fmu >= 0 && flv >= 0) { iWmu = fmu; iWlv = flv; }
    if (fam >= 0 && fal >= 0) { iamu = fam; ialv = fal; }
  }
  const void* adj = d_in[iadj];
  char* ws = (char*)d_ws;
  const size_t KB = 1024, MB = 1024 * 1024;
  // ---- workspace (<= 33 MB) ----
  float* wh1   = (float*)(ws + 0);                 // 8MB [dead after sd1/transpose1]
  float* whmu  = (float*)(ws + 0);                 // 2MB [overlay]
  float* whlv  = (float*)(ws + 2 * MB);            // 2MB [overlay]
  float* muf   = (float*)(ws + 4 * MB);            // 2MB [overlay]
  float* lvf   = (float*)(ws + 6 * MB);            // 2MB [overlay]
  u16*   xbf   = (u16*)(ws + 8 * MB);              // 8MB bf16 x [dead after gemm1]
  u16*   whT1  = (u16*)(ws + 8 * MB);              // 4MB bf16 [256][8192] [overlay]
  u16*   hbf   = (u16*)(ws + 12 * MB);             // 4MB bf16 [8192][256]
  u16*   whmuT = (u16*)(ws + 20 * MB);             // 1MB bf16 [64][8192]
  u16*   whlvT = (u16*)(ws + 21 * MB);             // 1MB bf16 [64][8192]
  u16*   W1T   = (u16*)(ws + 22 * MB);             // 256KB bf16 [256][512]
  u16*   WmuT  = (u16*)(ws + 22 * MB + 256 * KB);  // 32KB bf16 [64][256]
  u16*   WlvT  = (u16*)(ws + 22 * MB + 288 * KB);  // 32KB bf16 [64][256]
  float* s1    = (float*)(ws + 24 * MB + 96 * KB);
  float* d1    = (float*)(ws + 24 * MB + 128 * KB);
  float* smu   = (float*)(ws + 24 * MB + 160 * KB);
  float* dmu   = (float*)(ws + 24 * MB + 192 * KB);
  float* slv   = (float*)(ws + 24 * MB + 224 * KB);
  float* dlv   = (float*)(ws + 24 * MB + 256 * KB);
  float* dmaxv = (float*)(ws + 24 * MB + 288 * KB);  // 3 cells, 64B apart
  unsigned* mode  = (unsigned*)(ws + 24 * MB + 289 * KB);
  unsigned* amode = (unsigned*)(ws + 24 * MB + 290 * KB);
  unsigned char* abits = (unsigned char*)(ws + 25 * MB);  // 8MB bitmask

  // fp32 output layout: [logits 8192*16 | mu 8192*64 | logvar 8192*64]
  float* out_logits = (float*)d_out;
  float* out_mu     = (float*)d_out + 131072;
  float* out_lv     = (float*)d_out + 655360;

  detect3<<<1, 256, 0, stream>>>((const u16*)d_in[ix], mode);
  detect_adj<<<1, 256, 0, stream>>>((const unsigned*)adj, amode);
  adj_bits<<<2048, 256, 0, stream>>>(adj, abits, amode);

  // layer 1: xbf/W1T bf16, Wh1 = xbf @ W1T^T (MFMA), WhT1 bf16, s/d + dmax,
  // JS=1 flash (256 blocks x 1024 thr, bitmask adjacency, fused elu->hbf)
  convert_bf16<<<2048, 256, 0, stream>>>(d_in[ix], xbf, 524288, mode);
  transpose_any<<<dim3(16, 8), 256, 0, stream>>>(d_in[iW1], W1T, 512, 256, mode);
  gemm_mfma<<<dim3(4, 128), 256, 0, stream>>>(xbf, W1T, wh1, 512, 256);
  transpose_bf16<<<dim3(256, 8), 256, 0, stream>>>(wh1, whT1, 8192, 256);
  sd_f32<<<2048, 256, 0, stream>>>(wh1, d_in[ia1], s1, d1, 256, mode);
  dmax_reduce<<<1, 256, 0, stream>>>(d1, d1, dmaxv + 0);
  flash_mfma<1><<<256, 1024, 0, stream>>>(whT1, nullptr, s1, d1,
      nullptr, nullptr, dmaxv + 0, nullptr, abits,
      hbf, nullptr, nullptr, nullptr);

  // layers 2/3: dual MFMA GEMM from hbf, dual transposes, dual s/d + dmax,
  // FUSED JS=1 flash (bitmask adjacency, fused div + dual store)
  transpose_w2<<<dim3(8, 2, 2), 256, 0, stream>>>(d_in[iWmu], d_in[iWlv],
      WmuT, WlvT, 256, 64, mode);
  gemm2_dual<<<dim3(2, 128), 256, 0, stream>>>(hbf, WmuT, WlvT, whmu, whlv);
  transpose_pair<<<dim3(256, 2, 2), 256, 0, stream>>>(whmu, whlv, whmuT, whlvT,
      8192, 64);
  sd_dual<<<dim3(2048, 2), 256, 0, stream>>>(whmu, whlv, d_in[iamu], d_in[ialv],
      smu, slv, dmu, dlv, mode);
  dmax_reduce<<<2, 256, 0, stream>>>(dmu, dlv, dmaxv + 16);
  flash_mfma<2><<<256, 1024, 0, stream>>>(whmuT, whlvT, smu, dmu, slv, dlv,
      dmaxv + 16, dmaxv + 32, abits,
      muf, out_mu, lvf, out_lv);

  logits_f32<<<256, 256, 0, stream>>>(muf, lvf, d_in[ieps], d_in[iWc], d_in[ibc], out_logits, mode);
}

// Round 8
// 736.536 us; speedup vs baseline: 1.1563x; 1.1563x over previous
//
#include <hip/hip_runtime.h>

typedef unsigned short u16;
typedef __attribute__((ext_vector_type(8))) short short8;
typedef __attribute__((ext_vector_type(4))) float f32x4;

#define NROW 8192

__device__ __forceinline__ float bf2f(u16 h) {
  unsigned u = ((unsigned)h) << 16;
  return __builtin_bit_cast(float, u);
}
// mode-aware load: f32 ? fp32 storage : bf16 storage (upcast)
__device__ __forceinline__ float ldf(const void* p, size_t i, int f32) {
  return f32 ? ((const float*)p)[i] : bf2f(((const u16*)p)[i]);
}
// fp32 -> bf16 round-to-nearest-even
__device__ __forceinline__ u16 f2bf(float f) {
  unsigned b = __builtin_bit_cast(unsigned, f);
  b += 0x7FFFu + ((b >> 16) & 1u);
  return (u16)(b >> 16);
}

// ---- storage-dtype detection on x (N(0,1)).
__global__ void detect3(const u16* __restrict__ xr, unsigned* __restrict__ mode) {
  __shared__ int zc, bg;
  int t = threadIdx.x;   // 256
  if (t == 0) { zc = 0; bg = 0; }
  __syncthreads();
  int zeros_even = 0; int big = 0;
  for (int i = t; i < 4096; i += 256) {
    u16 v = xr[i];
    if (!(i & 1) && v == 0) zeros_even++;
    if (fabsf(bf2f(v)) > 1e6f) big = 1;
  }
  atomicAdd(&zc, zeros_even);
  if (big) atomicOr(&bg, 1);
  __syncthreads();
  if (t == 0) *mode = (zc > 512 || bg) ? 1u : 0u;   // 1 = fp32 storage
}

// ---- adj storage detection (u32 pair pattern 0x00003F80 unique to bf16).
__global__ void detect_adj(const unsigned* __restrict__ a, unsigned* __restrict__ amode) {
  __shared__ int clo;
  int t = threadIdx.x;   // 256
  if (t == 0) clo = 0;
  __syncthreads();
  int c = 0;
  for (int i = t; i < 4096; i += 256)
    if (a[i] == 0x00003F80u) c++;
  atomicAdd(&clo, c);
  __syncthreads();
  if (t == 0) *amode = (clo > 32) ? 1u : 0u;   // 1 = bf16 storage
}

// ---- adjacency -> bitmask (8 MB). byte b covers elements [b*8, b*8+8),
// bit q = (elem b*8+q != 0). Fully coalesced read/write; one streaming pass.
__global__ __launch_bounds__(256) void adj_bits(const void* __restrict__ adj,
    unsigned char* __restrict__ bits, const unsigned* __restrict__ amodep) {
  int amode = (int)*amodep;
  for (size_t b = (size_t)blockIdx.x * 256 + threadIdx.x; b < 8388608; b += 524288) {
    size_t e0 = b * 8;
    unsigned byte = 0;
    if (amode == 0) {          // u32/f32 storage
      int4 a0 = *(const int4*)((const int*)adj + e0);
      int4 a1 = *(const int4*)((const int*)adj + e0 + 4);
      byte = (a0.x != 0) | ((a0.y != 0) << 1) | ((a0.z != 0) << 2) | ((a0.w != 0) << 3) |
             ((a1.x != 0) << 4) | ((a1.y != 0) << 5) | ((a1.z != 0) << 6) | ((a1.w != 0) << 7);
    } else {                   // bf16 storage
      ushort4 a0 = *(const ushort4*)((const u16*)adj + e0);
      ushort4 a1 = *(const ushort4*)((const u16*)adj + e0 + 4);
      byte = (a0.x != 0) | ((a0.y != 0) << 1) | ((a0.z != 0) << 2) | ((a0.w != 0) << 3) |
             ((a1.x != 0) << 4) | ((a1.y != 0) << 5) | ((a1.z != 0) << 6) | ((a1.w != 0) << 7);
    }
    bits[b] = (unsigned char)byte;
  }
}

// C[M x N] fp32 = Abf[M x K] @ BT[N x K]^T, all bf16 operands, MFMA, no LDS.
// grid (N/64, M/64), 256 threads; wave w owns rows w*16..+15, 4 n-tiles.
__global__ __launch_bounds__(256) void gemm_mfma(const u16* __restrict__ Abf,
    const u16* __restrict__ BT, float* __restrict__ C, int K, int N) {
  int tid = threadIdx.x;
  int l = tid & 63, w = tid >> 6;
  int m0 = blockIdx.y * 64, n0 = blockIdx.x * 64;
  const u16* arow = Abf + (size_t)(m0 + w * 16 + (l & 15)) * K + (l >> 4) * 8;
  const u16* brow = BT + (size_t)(n0 + (l & 15)) * K + (l >> 4) * 8;
  f32x4 acc[4];
#pragma unroll
  for (int nt = 0; nt < 4; ++nt) acc[nt] = (f32x4){0.f, 0.f, 0.f, 0.f};
  for (int k0 = 0; k0 < K; k0 += 32) {
    short8 a = *(const short8*)(arow + k0);
#pragma unroll
    for (int nt = 0; nt < 4; ++nt) {
      short8 b = *(const short8*)(brow + (size_t)nt * 16 * K + k0);
      acc[nt] = __builtin_amdgcn_mfma_f32_16x16x32_bf16(a, b, acc[nt], 0, 0, 0);
    }
  }
  // C/D layout: col = lane&15, row = (lane>>4)*4 + q
#pragma unroll
  for (int nt = 0; nt < 4; ++nt)
#pragma unroll
    for (int q = 0; q < 4; ++q)
      C[(size_t)(m0 + w * 16 + (l >> 4) * 4 + q) * N + n0 + nt * 16 + (l & 15)] =
          acc[nt][q];
}

// Layer-2/3 dual GEMM: C{0,1}[8192 x 64] fp32 = hbf[8192 x 256] @ BT{0,1}[64 x 256]^T.
__global__ __launch_bounds__(256) void gemm2_dual(const u16* __restrict__ Abf,
    const u16* __restrict__ BT0, const u16* __restrict__ BT1,
    float* __restrict__ C0, float* __restrict__ C1) {
  const int K = 256, N = 64;
  const u16* BT = blockIdx.x ? BT1 : BT0;
  float* C = blockIdx.x ? C1 : C0;
  int tid = threadIdx.x, l = tid & 63, w = tid >> 6;
  int m0 = blockIdx.y * 64;
  const u16* arow = Abf + (size_t)(m0 + w * 16 + (l & 15)) * K + (l >> 4) * 8;
  const u16* brow = BT + (size_t)(l & 15) * K + (l >> 4) * 8;
  f32x4 acc[4];
#pragma unroll
  for (int nt = 0; nt < 4; ++nt) acc[nt] = (f32x4){0.f, 0.f, 0.f, 0.f};
  for (int k0 = 0; k0 < K; k0 += 32) {
    short8 a = *(const short8*)(arow + k0);
#pragma unroll
    for (int nt = 0; nt < 4; ++nt) {
      short8 b = *(const short8*)(brow + (size_t)nt * 16 * K + k0);
      acc[nt] = __builtin_amdgcn_mfma_f32_16x16x32_bf16(a, b, acc[nt], 0, 0, 0);
    }
  }
#pragma unroll
  for (int nt = 0; nt < 4; ++nt)
#pragma unroll
    for (int q = 0; q < 4; ++q)
      C[(size_t)(m0 + w * 16 + (l >> 4) * 4 + q) * N + nt * 16 + (l & 15)] = acc[nt][q];
}

// bf16 copy of a mode-aware buffer (8 elems/thread). n8 = elems/8.
__global__ __launch_bounds__(256) void convert_bf16(const void* __restrict__ in,
    u16* __restrict__ out, int n8, const unsigned* __restrict__ modep) {
  int f32 = (int)*modep;
  int i = blockIdx.x * 256 + threadIdx.x;
  if (i >= n8) return;
  if (f32) {
    float4 v0 = ((const float4*)in)[(size_t)i * 2];
    float4 v1 = ((const float4*)in)[(size_t)i * 2 + 1];
    ushort4 o0 = {f2bf(v0.x), f2bf(v0.y), f2bf(v0.z), f2bf(v0.w)};
    ushort4 o1 = {f2bf(v1.x), f2bf(v1.y), f2bf(v1.z), f2bf(v1.w)};
    ((ushort4*)out)[(size_t)i * 2] = o0;
    ((ushort4*)out)[(size_t)i * 2 + 1] = o1;
  } else {
    ((int4*)out)[i] = ((const int4*)in)[i];   // already bf16: raw copy
  }
}

// transpose + bf16 convert: in fp32 [M][F] -> out bf16 [F][M]. grid (M/32, F/32).
__global__ __launch_bounds__(256) void transpose_bf16(const float* __restrict__ in,
    u16* __restrict__ out, int M, int F) {
  __shared__ float t[32][33];
  int m0 = blockIdx.x * 32, f0 = blockIdx.y * 32;
  int c = threadIdx.x & 31, r = threadIdx.x >> 5;   // r = 0..7
  for (int rr = r; rr < 32; rr += 8)
    t[rr][c] = in[(size_t)(m0 + rr) * F + f0 + c];
  __syncthreads();
  for (int rr = r; rr < 32; rr += 8)
    out[(size_t)(f0 + rr) * M + m0 + c] = f2bf(t[c][rr]);
}

// dual fp32->bf16 transpose (whmu/whlv -> whmuT/whlvT). grid (M/32, F/32, 2).
__global__ __launch_bounds__(256) void transpose_pair(const float* __restrict__ in0,
    const float* __restrict__ in1, u16* __restrict__ out0, u16* __restrict__ out1,
    int M, int F) {
  const float* in = blockIdx.z ? in1 : in0;
  u16* out = blockIdx.z ? out1 : out0;
  __shared__ float t[32][33];
  int m0 = blockIdx.x * 32, f0 = blockIdx.y * 32;
  int c = threadIdx.x & 31, r = threadIdx.x >> 5;
  for (int rr = r; rr < 32; rr += 8)
    t[rr][c] = in[(size_t)(m0 + rr) * F + f0 + c];
  __syncthreads();
  for (int rr = r; rr < 32; rr += 8)
    out[(size_t)(f0 + rr) * M + m0 + c] = f2bf(t[c][rr]);
}

// transpose + bf16 convert from a RAW (mode-aware) buffer. grid (M/32, F/32).
__global__ __launch_bounds__(256) void transpose_any(const void* __restrict__ in,
    u16* __restrict__ out, int M, int F, const unsigned* __restrict__ modep) {
  int f32 = (int)*modep;
  __shared__ u16 t[32][33];
  int m0 = blockIdx.x * 32, f0 = blockIdx.y * 32;
  int c = threadIdx.x & 31, r = threadIdx.x >> 5;
  for (int rr = r; rr < 32; rr += 8)
    t[rr][c] = f2bf(ldf(in, (size_t)(m0 + rr) * F + f0 + c, f32));
  __syncthreads();
  for (int rr = r; rr < 32; rr += 8)
    out[(size_t)(f0 + rr) * M + m0 + c] = t[c][rr];
}

// dual raw transpose (Wmu/Wlv -> WmuT/WlvT). grid (M/32, F/32, 2).
__global__ __launch_bounds__(256) void transpose_w2(const void* __restrict__ in0,
    const void* __restrict__ in1, u16* __restrict__ out0, u16* __restrict__ out1,
    int M, int F, const unsigned* __restrict__ modep) {
  int f32 = (int)*modep;
  const void* in = blockIdx.z ? in1 : in0;
  u16* out = blockIdx.z ? out1 : out0;
  __shared__ u16 t[32][33];
  int m0 = blockIdx.x * 32, f0 = blockIdx.y * 32;
  int c = threadIdx.x & 31, r = threadIdx.x >> 5;
  for (int rr = r; rr < 32; rr += 8)
    t[rr][c] = f2bf(ldf(in, (size_t)(m0 + rr) * F + f0 + c, f32));
  __syncthreads();
  for (int rr = r; rr < 32; rr += 8)
    out[(size_t)(f0 + rr) * M + m0 + c] = t[c][rr];
}

// s_i = Wh_i . a[:F], d_i = Wh_i . a[F:] (Wh fp32, a raw). NO atomics.
__global__ __launch_bounds__(256) void sd_f32(const float* __restrict__ Wh,
    const void* __restrict__ a2, float* __restrict__ s, float* __restrict__ d,
    int F, const unsigned* __restrict__ modep) {
  int f32 = (int)*modep;
  int row = blockIdx.x * 4 + (threadIdx.x >> 6);
  int l = threadIdx.x & 63;
  float ss = 0.f, dd = 0.f;
  for (int k = l; k < F; k += 64) {
    float wv = Wh[(size_t)row * F + k];
    ss += wv * ldf(a2, k, f32);
    dd += wv * ldf(a2, F + k, f32);
  }
#pragma unroll
  for (int off = 32; off > 0; off >>= 1) {
    ss += __shfl_down(ss, off, 64);
    dd += __shfl_down(dd, off, 64);
  }
  if (l == 0) { s[row] = ss; d[row] = dd; }
}

// dual s/d for layers 2/3 (F = 64). grid (2048, 2). NO atomics.
__global__ __launch_bounds__(256) void sd_dual(const float* __restrict__ Wh0,
    const float* __restrict__ Wh1, const void* __restrict__ a0,
    const void* __restrict__ a1, float* __restrict__ s0, float* __restrict__ s1,
    float* __restrict__ d0, float* __restrict__ d1,
    const unsigned* __restrict__ modep) {
  int f32 = (int)*modep;
  int L = blockIdx.y;
  const float* Wh = L ? Wh1 : Wh0;
  const void* a2 = L ? a1 : a0;
  int row = blockIdx.x * 4 + (threadIdx.x >> 6);
  int l = threadIdx.x & 63;
  float wv = Wh[(size_t)row * 64 + l];
  float ss = wv * ldf(a2, l, f32);
  float dd = wv * ldf(a2, 64 + l, f32);
#pragma unroll
  for (int off = 32; off > 0; off >>= 1) {
    ss += __shfl_down(ss, off, 64);
    dd += __shfl_down(dd, off, 64);
  }
  if (l == 0) { (L ? s1 : s0)[row] = ss; (L ? d1 : d0)[row] = dd; }
}

// Dmax: single block per array, LDS tree, plain store. grid = #arrays.
__global__ __launch_bounds__(256) void dmax_reduce(const float* __restrict__ da,
    const float* __restrict__ db, float* __restrict__ cells) {
  const float* d = blockIdx.x ? db : da;
  __shared__ float red[256];
  float m = -3.4e38f;
  for (int i = threadIdx.x; i < NROW; i += 256) m = fmaxf(m, d[i]);
  red[threadIdx.x] = m;
  __syncthreads();
#pragma unroll
  for (int sft = 128; sft > 0; sft >>= 1) {
    if (threadIdx.x < sft) red[threadIdx.x] = fmaxf(red[threadIdx.x], red[threadIdx.x + sft]);
    __syncthreads();
  }
  if (threadIdx.x == 0) cells[blockIdx.x * 16] = red[0];
}

// swizzled P-fragment LDS byte offset:
// slot = L*8 + ks*2 + mh (1KB each, ks 0..3); within: [row 0..15][kg 0..3] x
// 8 bf16, kg XOR'd with (row>>1)&3 to spread banks on b128 write/read.
__device__ __forceinline__ int pa_off(int L, int ks, int mh, int row, int kg) {
  return ((L * 8 + ks * 2 + mh) << 10) + (row << 6) + ((kg ^ ((row >> 1) & 3)) << 4);
}

// Flash GAT layer(s) on MFMA — JS=1: each block owns 32 output rows COMPLETELY.
// grid = 256 blocks x 512 threads (8 waves). ZERO global atomics.
// j-tile = 128 per iteration (NIT=64), ks=0..3. Adjacency from the 8 MB
// BITMASK (1 byte/thread/iter, depth-2 reg prefetch) -> whT stays L2-resident.
// __launch_bounds__(512, 2): VGPR cap 256, bfr[4][NTW] (32 VGPR) stays in regs.
// Pipeline: raw s_barrier + lgkmcnt-only fence, PA double-buffered, setprio.
// NL=1 (FDIM=256): waves 0-7 each own 2 n-tiles, both m-halves.
// NL=2 (FDIM=64): waves 0-3 layer a, 4-7 layer b, 1 n-tile each, both m-halves.
template <int NL>
__global__ __launch_bounds__(512, 2) void flash_mfma(
    const u16* __restrict__ whTa, const u16* __restrict__ whTb,   // bf16 [FDIM][NROW]
    const float* __restrict__ sa, const float* __restrict__ da,
    const float* __restrict__ sb, const float* __restrict__ db,
    const float* __restrict__ cella, const float* __restrict__ cellb,
    const unsigned char* __restrict__ abits,
    void* __restrict__ o0, void* __restrict__ o1,
    void* __restrict__ o2, void* __restrict__ o3) {
  constexpr int NIT = NROW / 128;            // 64 iterations
  constexpr int NTW = (NL == 1) ? 2 : 1;     // n-tiles per wave
  constexpr int FDIM = (NL == 1) ? 256 : 64;
  __shared__ __align__(16) char PA[2][NL * 8192];   // double-buffered P frags
  __shared__ __align__(16) float dd_[NL][NROW];     // full d_j (prologue stage)
  __shared__ float sv_[NL][32], Ms_[NL][32], ls_[NL][32];
  int tid = threadIdx.x;
  int r0 = blockIdx.x * 32;
  if (tid < 32 * NL) {
    int L = tid >> 5, i = tid & 31;
    float Dm = L ? *cellb : *cella;
    float t0 = (L ? sb : sa)[r0 + i];
    sv_[L][i] = t0;
    float m = t0 + Dm;
    Ms_[L][i] = fmaxf(m, 0.2f * m);   // lrelu(s_i + Dmax) >= all e[i,:]
  }
  // stage the full d_j array (float4 coalesced)
  for (int u = tid; u < NL * (NROW / 4); u += 512) {
    int L = u / (NROW / 4), uu = u - L * (NROW / 4);
    ((float4*)dd_[L])[uu] = ((const float4*)(L ? db : da))[uu];
  }
  __syncthreads();
  // score-phase mapping: 32 rows x 16 j-octets (8 j each)
  int sr = tid >> 4, sjo = tid & 15;
  int ks_w = sjo >> 2, kg_w = sjo & 3, mh_w = sr >> 4, row_w = sr & 15;
  // PV-phase mapping
  int l = tid & 63, w = tid >> 6;            // w = 0..7
  int layer = (NL == 1) ? 0 : (w >> 2);
  int ntb = (NL == 1) ? (w * 2) : (w & 3);
  const u16* whT = layer ? whTb : whTa;
  f32x4 acc[2][NTW];
#pragma unroll
  for (int m = 0; m < 2; ++m)
#pragma unroll
    for (int n = 0; n < NTW; ++n) acc[m][n] = (f32x4){0.f, 0.f, 0.f, 0.f};
  float psum[NL];
#pragma unroll
  for (int L = 0; L < NL; ++L) psum[L] = 0.f;
  int bofs = (r0 + sr) * 1024 + sjo;         // bitmask byte index (16 B/iter)

  // adjacency-bit prefetch: depth 2 (static rotation)
  unsigned char abA = abits[bofs];
  unsigned char abB = abits[bofs + 16];
  for (int it = 0; it < NIT; ++it) {
    int j0 = it * 128;
    int cur = it & 1;
    // B fragments for this tile (issued first; L2-hit latency hidden by score)
    short8 bfr[4][NTW];
#pragma unroll
    for (int ks = 0; ks < 4; ++ks) {
      size_t jcol = (size_t)(j0 + ks * 32 + (l >> 4) * 8);
#pragma unroll
      for (int nt = 0; nt < NTW; ++nt)
        bfr[ks][nt] =
            *(const short8*)&whT[(size_t)((ntb + nt) * 16 + (l & 15)) * NROW + jcol];
    }
    // prefetch adjacency bits two iterations ahead
    unsigned char abN = abB;
    if (it + 2 < NIT) abN = abits[bofs + (it + 2) * 16];
    // ---- score phase: P[sr, j0+sjo*8 .. +7] in bf16 into PA[cur]
    char* pab = PA[cur];
#pragma unroll
    for (int L = 0; L < NL; ++L) {
      float sv = sv_[L][sr], Mr = Ms_[L][sr];
      float4 dv0 = *(const float4*)&dd_[L][j0 + sjo * 8];
      float4 dv1 = *(const float4*)&dd_[L][j0 + sjo * 8 + 4];
      float dvv[8] = {dv0.x, dv0.y, dv0.z, dv0.w, dv1.x, dv1.y, dv1.z, dv1.w};
      short8 pk;
      float ps = 0.f;
#pragma unroll
      for (int q = 0; q < 8; ++q) {
        float t = sv + dvv[q];
        float e = fmaxf(t, 0.2f * t) - Mr;           // <= 0
        float p = ((abA >> q) & 1) ? __expf(e) : 0.f;
        ps += p;
        pk[q] = (short)f2bf(p);
      }
      psum[L] += ps;
      *(short8*)(pab + pa_off(L, ks_w, mh_w, row_w, kg_w)) = pk;
    }
    // LDS-only fence + raw barrier: global loads stay outstanding
    asm volatile("s_waitcnt lgkmcnt(0)" ::: "memory");
    __builtin_amdgcn_s_barrier();
    __builtin_amdgcn_sched_barrier(0);
    // ---- PV phase: acc += P * WhT^T (MFMA)
    __builtin_amdgcn_s_setprio(1);
#pragma unroll
    for (int ks = 0; ks < 4; ++ks) {
      short8 a0 = *(const short8*)(pab + pa_off(layer, ks, 0, l & 15, l >> 4));
      short8 a1 = *(const short8*)(pab + pa_off(layer, ks, 1, l & 15, l >> 4));
#pragma unroll
      for (int nt = 0; nt < NTW; ++nt) {
        acc[0][nt] = __builtin_amdgcn_mfma_f32_16x16x32_bf16(a0, bfr[ks][nt],
                                                             acc[0][nt], 0, 0, 0);
        acc[1][nt] = __builtin_amdgcn_mfma_f32_16x16x32_bf16(a1, bfr[ks][nt],
                                                             acc[1][nt], 0, 0, 0);
      }
    }
    __builtin_amdgcn_s_setprio(0);
    // no second barrier: next score writes PA[cur^1]; its previous readers
    // (PV at it-1) completed before this iteration's barrier.
    abA = abB; abB = abN;
  }
  // ---- lsum: per-thread psum -> LDS (reuse PA) -> per-row sum (no atomics)
  __syncthreads();                    // last PV reads of PA done
  float* red = (float*)PA;
#pragma unroll
  for (int L = 0; L < NL; ++L) red[L * 512 + tid] = psum[L];
  __syncthreads();
  if (tid < 32 * NL) {
    int L = tid >> 5, r = tid & 31;
    float t = 0.f;
#pragma unroll
    for (int q = 0; q < 16; ++q) t += red[L * 512 + r * 16 + q];
    ls_[L][r] = t;
  }
  __syncthreads();
  // ---- fused epilogue (C/D layout: col=lane&15, row=(lane>>4)*4+q)
  if constexpr (NL == 1) {
    u16* hb = (u16*)o0;               // bf16 h = elu(acc/lsum)
#pragma unroll
    for (int m = 0; m < 2; ++m)
#pragma unroll
      for (int nt = 0; nt < NTW; ++nt)
#pragma unroll
        for (int q = 0; q < 4; ++q) {
          int r = m * 16 + (l >> 4) * 4 + q;
          int c = (ntb + nt) * 16 + (l & 15);
          float x = acc[m][nt][q] / ls_[0][r];
          x = (x > 0.f) ? x : (__expf(x) - 1.f);
          hb[(size_t)(r0 + r) * FDIM + c] = f2bf(x);
        }
  } else {
    float* of = (float*)(layer ? o2 : o0);   // ws copy
    float* od = (float*)(layer ? o3 : o1);   // d_out region
#pragma unroll
    for (int m = 0; m < 2; ++m)
#pragma unroll
      for (int q = 0; q < 4; ++q) {
        int r = m * 16 + (l >> 4) * 4 + q;
        int c = ntb * 16 + (l & 15);
        float x = acc[m][0][q] / ls_[layer][r];
        size_t idx = (size_t)(r0 + r) * FDIM + c;
        of[idx] = x;
        od[idx] = x;
      }
  }
}

// logits = (mu + eps*exp(0.5*logvar)) @ Wc + bc. 256 blocks x 32 rows.
__global__ __launch_bounds__(256) void logits_f32(const float* __restrict__ mu,
    const float* __restrict__ lv, const void* __restrict__ eps,
    const void* __restrict__ Wc, const void* __restrict__ bcv,
    float* __restrict__ outL, const unsigned* __restrict__ modep) {
  int f32 = (int)*modep;
  __shared__ float zs[32 * 64];
  __shared__ float wcs[64 * 16];
  int tid = threadIdx.x;
  for (int i = tid; i < 1024; i += 256) wcs[i] = ldf(Wc, i, f32);
  int row0 = blockIdx.x * 32;
  for (int i = tid; i < 2048; i += 256) {
    int r = i >> 6, c = i & 63;
    size_t g = (size_t)(row0 + r) * 64 + c;
    zs[i] = mu[g] + ldf(eps, g, f32) * __expf(0.5f * lv[g]);
  }
  __syncthreads();
  for (int it = tid; it < 512; it += 256) {
    int r = it >> 4, oc = it & 15;
    float a = ldf(bcv, oc, f32);
    for (int c = 0; c < 64; ++c) a += zs[r * 64 + c] * wcs[c * 16 + oc];
    outL[(size_t)(row0 + r) * 16 + oc] = a;
  }
}

extern "C" void kernel_launch(void* const* d_in, const int* in_sizes, int n_in,
                              void* d_out, int out_size, void* d_ws, size_t ws_size,
                              hipStream_t stream) {
  (void)out_size; (void)ws_size;
  // ---- size-based input resolution (robust to permutation; ties in dict order)
  int ix = 0, iadj = 1, ieps = 2, iW1 = 3, ia1 = 4, iWmu = 5, iamu = 6,
      iWlv = 7, ialv = 8, iWc = 9, ibc = 10;
  {
    int fmu = -1, flv = -1, fam = -1, fal = -1;
    for (int i = 0; i < n_in; ++i) {
      switch (in_sizes[i]) {
        case 67108864: iadj = i; break;
        case 4194304:  ix   = i; break;
        case 524288:   ieps = i; break;
        case 131072:   iW1  = i; break;
        case 512:      ia1  = i; break;
        case 1024:     iWc  = i; break;
        case 16:       ibc  = i; break;
        case 16384:    if (fmu < 0) fmu = i; else flv = i; break;
        case 128:      if (fam < 0) fam = i; else fal = i; break;
        default: break;
      }
    }
    if (fmu >= 0 && flv >= 0) { iWmu = fmu; iWlv = flv; }
    if (fam >= 0 && fal >= 0) { iamu = fam; ialv = fal; }
  }
  const void* adj = d_in[iadj];
  char* ws = (char*)d_ws;
  const size_t KB = 1024, MB = 1024 * 1024;
  // ---- workspace (<= 33 MB) ----
  float* wh1   = (float*)(ws + 0);                 // 8MB [dead after sd1/transpose1]
  float* whmu  = (float*)(ws + 0);                 // 2MB [overlay]
  float* whlv  = (float*)(ws + 2 * MB);            // 2MB [overlay]
  float* muf   = (float*)(ws + 4 * MB);            // 2MB [overlay]
  float* lvf   = (float*)(ws + 6 * MB);            // 2MB [overlay]
  u16*   xbf   = (u16*)(ws + 8 * MB);              // 8MB bf16 x [dead after gemm1]
  u16*   whT1  = (u16*)(ws + 8 * MB);              // 4MB bf16 [256][8192] [overlay]
  u16*   hbf   = (u16*)(ws + 12 * MB);             // 4MB bf16 [8192][256]
  u16*   whmuT = (u16*)(ws + 20 * MB);             // 1MB bf16 [64][8192]
  u16*   whlvT = (u16*)(ws + 21 * MB);             // 1MB bf16 [64][8192]
  u16*   W1T   = (u16*)(ws + 22 * MB);             // 256KB bf16 [256][512]
  u16*   WmuT  = (u16*)(ws + 22 * MB + 256 * KB);  // 32KB bf16 [64][256]
  u16*   WlvT  = (u16*)(ws + 22 * MB + 288 * KB);  // 32KB bf16 [64][256]
  float* s1    = (float*)(ws + 24 * MB + 96 * KB);
  float* d1    = (float*)(ws + 24 * MB + 128 * KB);
  float* smu   = (float*)(ws + 24 * MB + 160 * KB);
  float* dmu   = (float*)(ws + 24 * MB + 192 * KB);
  float* slv   = (float*)(ws + 24 * MB + 224 * KB);
  float* dlv   = (float*)(ws + 24 * MB + 256 * KB);
  float* dmaxv = (float*)(ws + 24 * MB + 288 * KB);  // 3 cells, 64B apart
  unsigned* mode  = (unsigned*)(ws + 24 * MB + 289 * KB);
  unsigned* amode = (unsigned*)(ws + 24 * MB + 290 * KB);
  unsigned char* abits = (unsigned char*)(ws + 25 * MB);  // 8MB bitmask

  // fp32 output layout: [logits 8192*16 | mu 8192*64 | logvar 8192*64]
  float* out_logits = (float*)d_out;
  float* out_mu     = (float*)d_out + 131072;
  float* out_lv     = (float*)d_out + 655360;

  detect3<<<1, 256, 0, stream>>>((const u16*)d_in[ix], mode);
  detect_adj<<<1, 256, 0, stream>>>((const unsigned*)adj, amode);
  adj_bits<<<2048, 256, 0, stream>>>(adj, abits, amode);

  // layer 1: xbf/W1T bf16, Wh1 = xbf @ W1T^T (MFMA), WhT1 bf16, s/d + dmax,
  // JS=1 flash (256 blocks x 512 thr, bitmask adjacency, fused elu->hbf)
  convert_bf16<<<2048, 256, 0, stream>>>(d_in[ix], xbf, 524288, mode);
  transpose_any<<<dim3(16, 8), 256, 0, stream>>>(d_in[iW1], W1T, 512, 256, mode);
  gemm_mfma<<<dim3(4, 128), 256, 0, stream>>>(xbf, W1T, wh1, 512, 256);
  transpose_bf16<<<dim3(256, 8), 256, 0, stream>>>(wh1, whT1, 8192, 256);
  sd_f32<<<2048, 256, 0, stream>>>(wh1, d_in[ia1], s1, d1, 256, mode);
  dmax_reduce<<<1, 256, 0, stream>>>(d1, d1, dmaxv + 0);
  flash_mfma<1><<<256, 512, 0, stream>>>(whT1, nullptr, s1, d1,
      nullptr, nullptr, dmaxv + 0, nullptr, abits,
      hbf, nullptr, nullptr, nullptr);

  // layers 2/3: dual MFMA GEMM from hbf, dual transposes, dual s/d + dmax,
  // FUSED JS=1 flash (bitmask adjacency, fused div + dual store)
  transpose_w2<<<dim3(8, 2, 2), 256, 0, stream>>>(d_in[iWmu], d_in[iWlv],
      WmuT, WlvT, 256, 64, mode);
  gemm2_dual<<<dim3(2, 128), 256, 0, stream>>>(hbf, WmuT, WlvT, whmu, whlv);
  transpose_pair<<<dim3(256, 2, 2), 256, 0, stream>>>(whmu, whlv, whmuT, whlvT,
      8192, 64);
  sd_dual<<<dim3(2048, 2), 256, 0, stream>>>(whmu, whlv, d_in[iamu], d_in[ialv],
      smu, slv, dmu, dlv, mode);
  dmax_reduce<<<2, 256, 0, stream>>>(dmu, dlv, dmaxv + 16);
  flash_mfma<2><<<256, 512, 0, stream>>>(whmuT, whlvT, smu, dmu, slv, dlv,
      dmaxv + 16, dmaxv + 32, abits,
      muf, out_mu, lvf, out_lv);

  logits_f32<<<256, 256, 0, stream>>>(muf, lvf, d_in[ieps], d_in[iWc], d_in[ibc], out_logits, mode);
}